// Round 1
// baseline (408.293 us; speedup 1.0000x reference)
//
#include <hip/hip_runtime.h>
#include <hip/hip_bf16.h>
#include <math.h>

typedef unsigned short ushort_t;
typedef __attribute__((ext_vector_type(8))) unsigned short ushort8;
typedef __attribute__((ext_vector_type(4))) unsigned short ushort4_t;
typedef __attribute__((ext_vector_type(8))) __bf16 bf16x8;
typedef __attribute__((ext_vector_type(4))) float f32x4;

__device__ inline ushort_t f2b(float f) {
  __hip_bfloat16 h = __float2bfloat16(f);
  return __builtin_bit_cast(ushort_t, h);
}
__device__ inline float b2f(ushort_t u) {
  __hip_bfloat16 h = __builtin_bit_cast(__hip_bfloat16, u);
  return __bfloat162float(h);
}

// ---------------- weights fp32 -> bf16 ----------------
__global__ __launch_bounds__(256) void prep_weights(
    const float* __restrict__ qkv_w, const float* __restrict__ proj_w,
    ushort_t* __restrict__ qkvw, ushort_t* __restrict__ projw) {
  int idx = blockIdx.x * 256 + threadIdx.x;
  const int NQ = 1536 * 512;
  if (idx < NQ) {
    qkvw[idx] = f2b(qkv_w[idx]);
  } else {
    int j = idx - NQ;
    if (j < 512 * 512) projw[j] = f2b(proj_w[j]);
  }
}

// ---------------- GroupNorm: one block per (batch, group) ----------------
__global__ __launch_bounds__(256) void gn_kernel(
    const float* __restrict__ x, const float* __restrict__ w,
    const float* __restrict__ bgn, ushort_t* __restrict__ xn) {
  const int tid = threadIdx.x;
  const int bg = blockIdx.x;  // [0, 64): batch*32 + group
  const size_t base = (size_t)bg * (16 * 4096);
  const float4* xv = (const float4*)(x + base);
  float s = 0.f, ss = 0.f;
  for (int i = tid; i < 16384; i += 256) {
    float4 v = xv[i];
    s += v.x + v.y + v.z + v.w;
    ss += v.x * v.x + v.y * v.y + v.z * v.z + v.w * v.w;
  }
  __shared__ float red[8];
  for (int off = 32; off > 0; off >>= 1) {
    s += __shfl_down(s, off);
    ss += __shfl_down(ss, off);
  }
  if ((tid & 63) == 0) { red[tid >> 6] = s; red[4 + (tid >> 6)] = ss; }
  __syncthreads();
  float st = red[0] + red[1] + red[2] + red[3];
  float sst = red[4] + red[5] + red[6] + red[7];
  float mean = st * (1.f / 65536.f);
  float var = sst * (1.f / 65536.f) - mean * mean;
  float inv = rsqrtf(var + 1e-6f);
  const int g = bg & 31;
  ushort_t* out = xn + base;
  for (int i = tid; i < 16384; i += 256) {
    float4 v = xv[i];
    int c = (g << 4) + (i >> 10);  // channel: each channel = 1024 float4s
    float wc = w[c] * inv;
    float bc = bgn[c] - mean * wc;
    ushort4_t o;
    o[0] = f2b(v.x * wc + bc);
    o[1] = f2b(v.y * wc + bc);
    o[2] = f2b(v.z * wc + bc);
    o[3] = f2b(v.w * wc + bc);
    *(ushort4_t*)(out + (size_t)i * 4) = o;
  }
}

// ---------------- generic bf16 MFMA GEMM ----------------
// C[m,n] = sum_k A[m,k] * B[k,n]   (A: [M][lda] row-major, or [K][lda] if TRANS_A)
// EPI: 0 = +bias, bf16 out; 1 = *scale, bf16 out; 2 = bf16 out; 3 = +bias+resid, f32 out
template <int TRANS_A, int EPI>
__global__ __launch_bounds__(256) void gemm_k(
    const ushort_t* __restrict__ Ag, const ushort_t* __restrict__ Bg,
    void* __restrict__ Cg, const float* __restrict__ bias,
    const float* __restrict__ resid, int M, int N, int K, int lda,
    size_t sA, size_t sB, size_t sC, float scale) {
  __shared__ ushort_t As[128][40];  // [m][k], pad 32->40 shorts
  __shared__ ushort_t Bs[128][40];  // [n][k] (transposed)
  const int tid = threadIdx.x;
  const int bz = blockIdx.z;
  Ag += bz * sA;
  Bg += bz * sB;
  const int bm0 = blockIdx.y * 128;
  const int bn0 = blockIdx.x * 128;

  f32x4 acc[4][4] = {};

  const int w = tid >> 6, lane = tid & 63;
  const int wm = (w >> 1) * 64, wn = (w & 1) * 64;
  const int fr = lane & 15, fk = (lane >> 4) * 8;

  for (int kk = 0; kk < K; kk += 32) {
    if (!TRANS_A) {
      int m = tid >> 1, k0 = (tid & 1) * 16;
      const ushort8* src = (const ushort8*)(Ag + (size_t)(bm0 + m) * lda + kk + k0);
      ushort8 a0 = src[0], a1 = src[1];
      *(ushort8*)&As[m][k0] = a0;
      *(ushort8*)&As[m][k0 + 8] = a1;
    } else {
      int k = tid >> 3, m0 = (tid & 7) << 4;
      const ushort8* src = (const ushort8*)(Ag + (size_t)(kk + k) * lda + bm0 + m0);
      ushort8 a0 = src[0], a1 = src[1];
#pragma unroll
      for (int i = 0; i < 8; i++) As[m0 + i][k] = a0[i];
#pragma unroll
      for (int i = 0; i < 8; i++) As[m0 + 8 + i][k] = a1[i];
    }
    {
      int k = tid >> 3, n0 = (tid & 7) << 4;
      const ushort8* src = (const ushort8*)(Bg + (size_t)(kk + k) * N + bn0 + n0);
      ushort8 b0 = src[0], b1 = src[1];
#pragma unroll
      for (int i = 0; i < 8; i++) Bs[n0 + i][k] = b0[i];
#pragma unroll
      for (int i = 0; i < 8; i++) Bs[n0 + 8 + i][k] = b1[i];
    }
    __syncthreads();
    bf16x8 af[4], bfr[4];
#pragma unroll
    for (int mi = 0; mi < 4; mi++)
      af[mi] = *(const bf16x8*)&As[wm + mi * 16 + fr][fk];
#pragma unroll
    for (int ni = 0; ni < 4; ni++)
      bfr[ni] = *(const bf16x8*)&Bs[wn + ni * 16 + fr][fk];
#pragma unroll
    for (int mi = 0; mi < 4; mi++)
#pragma unroll
      for (int ni = 0; ni < 4; ni++)
        acc[mi][ni] = __builtin_amdgcn_mfma_f32_16x16x32_bf16(
            af[mi], bfr[ni], acc[mi][ni], 0, 0, 0);
    __syncthreads();
  }

  const int r0 = (lane >> 4) * 4;
#pragma unroll
  for (int mi = 0; mi < 4; mi++) {
#pragma unroll
    for (int r = 0; r < 4; r++) {
      int gm = bm0 + wm + mi * 16 + r0 + r;
#pragma unroll
      for (int ni = 0; ni < 4; ni++) {
        int gn = bn0 + wn + ni * 16 + fr;
        float v = acc[mi][ni][r];
        size_t off = (size_t)gm * N + gn;
        if constexpr (EPI == 0) {
          ((ushort_t*)Cg)[bz * sC + off] = f2b(v + bias[gm]);
        } else if constexpr (EPI == 1) {
          ((ushort_t*)Cg)[bz * sC + off] = f2b(v * scale);
        } else if constexpr (EPI == 2) {
          ((ushort_t*)Cg)[bz * sC + off] = f2b(v);
        } else {
          ((float*)Cg)[bz * sC + off] = v + bias[gm] + resid[bz * sC + off];
        }
      }
    }
  }
}

// ---------------- row softmax, in place, one block per row ----------------
__global__ __launch_bounds__(256) void softmax_rows(ushort_t* __restrict__ L) {
  const int tid = threadIdx.x;
  ushort_t* row = L + (size_t)blockIdx.x * 4096;
  ushort8 r0 = ((ushort8*)row)[tid * 2];
  ushort8 r1 = ((ushort8*)row)[tid * 2 + 1];
  float v[16];
#pragma unroll
  for (int i = 0; i < 8; i++) { v[i] = b2f(r0[i]); v[8 + i] = b2f(r1[i]); }
  float m = -1e30f;
#pragma unroll
  for (int i = 0; i < 16; i++) m = fmaxf(m, v[i]);
  __shared__ float redm[4];
  __shared__ float reds[4];
  for (int off = 32; off > 0; off >>= 1) m = fmaxf(m, __shfl_down(m, off));
  if ((tid & 63) == 0) redm[tid >> 6] = m;
  __syncthreads();
  m = fmaxf(fmaxf(redm[0], redm[1]), fmaxf(redm[2], redm[3]));
  float s = 0.f;
#pragma unroll
  for (int i = 0; i < 16; i++) { v[i] = __expf(v[i] - m); s += v[i]; }
  for (int off = 32; off > 0; off >>= 1) s += __shfl_down(s, off);
  if ((tid & 63) == 0) reds[tid >> 6] = s;
  __syncthreads();
  s = reds[0] + reds[1] + reds[2] + reds[3];
  float rs = 1.0f / s;
  ushort8 o0, o1;
#pragma unroll
  for (int i = 0; i < 8; i++) { o0[i] = f2b(v[i] * rs); o1[i] = f2b(v[8 + i] * rs); }
  ((ushort8*)row)[tid * 2] = o0;
  ((ushort8*)row)[tid * 2 + 1] = o1;
}

extern "C" void kernel_launch(void* const* d_in, const int* in_sizes, int n_in,
                              void* d_out, int out_size, void* d_ws,
                              size_t ws_size, hipStream_t stream) {
  const float* x = (const float*)d_in[0];
  const float* gn_w = (const float*)d_in[1];
  const float* gn_b = (const float*)d_in[2];
  const float* qkv_w = (const float*)d_in[3];
  const float* qkv_b = (const float*)d_in[4];
  const float* proj_w = (const float*)d_in[5];
  const float* proj_b = (const float*)d_in[6];
  float* out = (float*)d_out;

  char* ws = (char*)d_ws;
  ushort_t* xn = (ushort_t*)ws;                       //  8,388,608 B
  ushort_t* qkvw = (ushort_t*)(ws + 8388608);         //  1,572,864 B
  ushort_t* projw = (ushort_t*)(ws + 9961472);        //    524,288 B
  ushort_t* qkv = (ushort_t*)(ws + 10485760);         // 25,165,824 B
  ushort_t* Lbuf = (ushort_t*)(ws + 35651584);        // 67,108,864 B
  ushort_t* Obuf = (ushort_t*)(ws + 102760448);       //  8,388,608 B

  const size_t sXN = (size_t)512 * 4096;
  const size_t sQKV = (size_t)1536 * 4096;
  const size_t sL = (size_t)4096 * 4096;

  prep_weights<<<4096, 256, 0, stream>>>(qkv_w, proj_w, qkvw, projw);
  gn_kernel<<<64, 256, 0, stream>>>(x, gn_w, gn_b, xn);
  // QKV: M=1536, N=4096, K=512
  gemm_k<0, 0><<<dim3(32, 12, 2), 256, 0, stream>>>(
      qkvw, xn, qkv, qkv_b, nullptr, 1536, 4096, 512, 512, 0, sXN, sQKV, 1.f);
  // L = scale * K^T Q: M=4096(p), N=4096(q), K=512(c); A = k-matrix [c][p] transposed
  gemm_k<1, 1><<<dim3(32, 32, 2), 256, 0, stream>>>(
      qkv + (size_t)512 * 4096, qkv, Lbuf, nullptr, nullptr, 4096, 4096, 512,
      4096, sQKV, sQKV, sL, 0.04419417382415922f);
  softmax_rows<<<8192, 256, 0, stream>>>(Lbuf);
  // O = V S: M=512(c), N=4096(i), K=4096(p)
  gemm_k<0, 2><<<dim3(32, 4, 2), 256, 0, stream>>>(
      qkv + (size_t)1024 * 4096, Lbuf, Obuf, nullptr, nullptr, 512, 4096, 4096,
      4096, sQKV, sL, sXN, 1.f);
  // proj + bias + residual: M=512, N=4096, K=512, fp32 out
  gemm_k<0, 3><<<dim3(32, 4, 2), 256, 0, stream>>>(
      projw, Obuf, out, proj_b, x, 512, 4096, 512, 512, 0, sXN, sXN, 1.f);
}

// Round 2
// 281.827 us; speedup vs baseline: 1.4487x; 1.4487x over previous
//
#include <hip/hip_runtime.h>
#include <hip/hip_bf16.h>
#include <math.h>

typedef unsigned short ushort_t;
typedef __attribute__((ext_vector_type(8))) unsigned short ushort8;
typedef __attribute__((ext_vector_type(4))) unsigned short ushort4_t;
typedef __attribute__((ext_vector_type(8))) __bf16 bf16x8;
typedef __attribute__((ext_vector_type(4))) float f32x4;

__device__ inline ushort_t f2b(float f) {
  __hip_bfloat16 h = __float2bfloat16(f);
  return __builtin_bit_cast(ushort_t, h);
}
__device__ inline float b2f(ushort_t u) {
  __hip_bfloat16 h = __builtin_bit_cast(__hip_bfloat16, u);
  return __bfloat162float(h);
}

__device__ inline void gload16(const ushort_t* g, ushort_t* l) {
  __builtin_amdgcn_global_load_lds(
      (const __attribute__((address_space(1))) unsigned int*)g,
      (__attribute__((address_space(3))) unsigned int*)l, 16, 0, 0);
}

// ---------------- weights fp32 -> bf16 ----------------
__global__ __launch_bounds__(256) void prep_weights(
    const float* __restrict__ qkv_w, const float* __restrict__ proj_w,
    ushort_t* __restrict__ qkvw, ushort_t* __restrict__ projw) {
  int idx = blockIdx.x * 256 + threadIdx.x;
  const int NQ = 1536 * 512;
  if (idx < NQ) {
    qkvw[idx] = f2b(qkv_w[idx]);
  } else {
    int j = idx - NQ;
    if (j < 512 * 512) projw[j] = f2b(proj_w[j]);
  }
}

// ---------------- GN stats: one block per (batch, group) ----------------
__global__ __launch_bounds__(256) void gn_stats(const float* __restrict__ x,
                                                float* __restrict__ stats) {
  const int tid = threadIdx.x;
  const int bg = blockIdx.x;  // b*32+g
  const float4* xv = (const float4*)(x + (size_t)bg * 65536);
  float s = 0.f, ss = 0.f;
  for (int i = tid; i < 16384; i += 256) {
    float4 v = xv[i];
    s += v.x + v.y + v.z + v.w;
    ss += v.x * v.x + v.y * v.y + v.z * v.z + v.w * v.w;
  }
  __shared__ float red[8];
  for (int off = 32; off > 0; off >>= 1) {
    s += __shfl_down(s, off);
    ss += __shfl_down(ss, off);
  }
  if ((tid & 63) == 0) { red[tid >> 6] = s; red[4 + (tid >> 6)] = ss; }
  __syncthreads();
  if (tid == 0) {
    float st = red[0] + red[1] + red[2] + red[3];
    float sst = red[4] + red[5] + red[6] + red[7];
    float mean = st * (1.f / 65536.f);
    float var = sst * (1.f / 65536.f) - mean * mean;
    stats[bg * 2] = mean;
    stats[bg * 2 + 1] = rsqrtf(var + 1e-6f);
  }
}

// ---------------- GN apply + transpose: xnT[p][c] bf16 ----------------
__global__ __launch_bounds__(256) void gn_apply_t(
    const float* __restrict__ x, const float* __restrict__ w,
    const float* __restrict__ bgn, const float* __restrict__ stats,
    ushort_t* __restrict__ xnT) {
  __shared__ ushort_t tile[64][68];
  const int b = blockIdx.z;
  const int p0 = blockIdx.x * 64, c0 = blockIdx.y * 64;
  const int tid = threadIdx.x;
  const float* xb = x + ((size_t)b * 512 + c0) * 4096 + p0;
  const int tc = tid >> 4, tp = (tid & 15) * 4;
#pragma unroll
  for (int pass = 0; pass < 4; ++pass) {
    int c = pass * 16 + tc;
    int cg = c0 + c;
    float mean = stats[(b * 32 + (cg >> 4)) * 2];
    float inv = stats[(b * 32 + (cg >> 4)) * 2 + 1];
    float wc = w[cg] * inv;
    float bc = bgn[cg] - mean * wc;
    float4 v = *(const float4*)(xb + (size_t)c * 4096 + tp);
    tile[c][tp] = f2b(v.x * wc + bc);
    tile[c][tp + 1] = f2b(v.y * wc + bc);
    tile[c][tp + 2] = f2b(v.z * wc + bc);
    tile[c][tp + 3] = f2b(v.w * wc + bc);
  }
  __syncthreads();
  const int c8 = (tid & 7) * 8;
#pragma unroll
  for (int pass = 0; pass < 2; ++pass) {
    int p = pass * 32 + (tid >> 3);
    ushort8 u;
#pragma unroll
    for (int e = 0; e < 8; ++e) u[e] = tile[c8 + e][p];
    *(ushort8*)(xnT + ((size_t)b * 4096 + p0 + p) * 512 + c0 + c8) = u;
  }
}

// ---------------- bt-form bf16 MFMA GEMM (m97 structure) ----------------
// C[m][n] = sum_k A[m][k] * B[n][k];  ldc = N
// EPI: 0 bf16 +bias[n]; 1 bf16 +bias[m]; 2 bf16 *scale; 3 bf16; 4 f32 +bias[m]+resid
template <int EPI>
__global__ __launch_bounds__(256) void gemm_bt(
    const ushort_t* __restrict__ A, const ushort_t* __restrict__ B,
    void* __restrict__ Cg, const float* __restrict__ bias,
    const float* __restrict__ resid, int N, int K, int lda, int ldb,
    size_t sA, size_t sB, size_t sC, float scale) {
  __shared__ __align__(16) ushort_t As[4096];  // [128][32]
  __shared__ __align__(16) ushort_t Bs[4096];
  const int bz = blockIdx.z;
  const ushort_t* Ab = A + bz * sA;
  const ushort_t* Bb = B + bz * sB;
  const int bm0 = blockIdx.y * 128, bn0 = blockIdx.x * 128;
  const int tid = threadIdx.x;
  const int w = tid >> 6, lane = tid & 63;
  const int sm = tid >> 2, sk = (tid & 3) * 8;
  const ushort_t* aS = Ab + (size_t)(bm0 + sm) * lda + sk;
  const ushort_t* bS = Bb + (size_t)(bn0 + sm) * ldb + sk;
  ushort_t* ldsA = As + w * 512;  // wave-uniform base
  ushort_t* ldsB = Bs + w * 512;
  const int wm = (w >> 1) * 64, wn = (w & 1) * 64;
  const int fr = lane & 15, fk = (lane >> 4) * 8;
  f32x4 acc[4][4] = {};
  for (int kk = 0; kk < K; kk += 32) {
    gload16(aS + kk, ldsA);
    gload16(aS + (size_t)64 * lda + kk, ldsA + 2048);
    gload16(bS + kk, ldsB);
    gload16(bS + (size_t)64 * ldb + kk, ldsB + 2048);
    __syncthreads();
    bf16x8 af[4], bfv[4];
#pragma unroll
    for (int mi = 0; mi < 4; mi++)
      af[mi] = *(const bf16x8*)&As[(wm + mi * 16 + fr) * 32 + fk];
#pragma unroll
    for (int ni = 0; ni < 4; ni++)
      bfv[ni] = *(const bf16x8*)&Bs[(wn + ni * 16 + fr) * 32 + fk];
#pragma unroll
    for (int mi = 0; mi < 4; mi++)
#pragma unroll
      for (int ni = 0; ni < 4; ni++)
        acc[mi][ni] = __builtin_amdgcn_mfma_f32_16x16x32_bf16(
            af[mi], bfv[ni], acc[mi][ni], 0, 0, 0);
    __syncthreads();
  }
  const int r0 = (lane >> 4) * 4;
  const size_t cbase = (size_t)bz * sC;
#pragma unroll
  for (int mi = 0; mi < 4; mi++) {
#pragma unroll
    for (int r = 0; r < 4; r++) {
      int gm = bm0 + wm + mi * 16 + r0 + r;
#pragma unroll
      for (int ni = 0; ni < 4; ni++) {
        int gn = bn0 + wn + ni * 16 + fr;
        float v = acc[mi][ni][r];
        size_t off = cbase + (size_t)gm * N + gn;
        if constexpr (EPI == 0) ((ushort_t*)Cg)[off] = f2b(v + bias[gn]);
        else if constexpr (EPI == 1) ((ushort_t*)Cg)[off] = f2b(v + bias[gm]);
        else if constexpr (EPI == 2) ((ushort_t*)Cg)[off] = f2b(v * scale);
        else if constexpr (EPI == 3) ((ushort_t*)Cg)[off] = f2b(v);
        else ((float*)Cg)[off] = v + bias[gm] + resid[off];
      }
    }
  }
}

// ---------------- column softmax over Lb rows (per column j) ----------------
// Lb[b][r][j], stats over r for each j. 3 stages.
__global__ __launch_bounds__(256) void sm_part(const ushort_t* __restrict__ Lb,
                                               float* __restrict__ part) {
  // grid (64 jblk, 8 rowchunk, 2 b); 64 cols x 4 row-subsets per block
  const int jl = threadIdx.x & 63, q = threadIdx.x >> 6;
  const int j = blockIdx.x * 64 + jl;
  const ushort_t* p = Lb + (size_t)blockIdx.z * 16777216 +
                      (size_t)(blockIdx.y * 512 + q * 128) * 4096 + j;
  float m = -3e38f, s = 0.f;
  for (int r = 0; r < 128; ++r) {
    float v = b2f(p[(size_t)r * 4096]);
    float nm = fmaxf(m, v);
    s = s * __expf(m - nm) + __expf(v - nm);
    m = nm;
  }
  __shared__ float rm[4][64], rsum[4][64];
  rm[q][jl] = m;
  rsum[q][jl] = s;
  __syncthreads();
  if (q == 0) {
    float M = rm[0][jl], S = rsum[0][jl];
#pragma unroll
    for (int i = 1; i < 4; i++) {
      float mi = rm[i][jl], si = rsum[i][jl];
      float nm = fmaxf(M, mi);
      S = S * __expf(M - nm) + si * __expf(mi - nm);
      M = nm;
    }
    size_t o = (((size_t)blockIdx.z * 8 + blockIdx.y) * 4096 + j) * 2;
    part[o] = M;
    part[o + 1] = S;
  }
}

__global__ __launch_bounds__(256) void sm_fin(const float* __restrict__ part,
                                              float* __restrict__ cs) {
  int idx = blockIdx.x * 256 + threadIdx.x;  // b*4096 + j
  int b = idx >> 12, j = idx & 4095;
  float M = -3e38f, S = 0.f;
#pragma unroll
  for (int rc = 0; rc < 8; rc++) {
    size_t o = (((size_t)b * 8 + rc) * 4096 + j) * 2;
    float mi = part[o], si = part[o + 1];
    float nm = fmaxf(M, mi);
    S = S * __expf(M - nm) + si * __expf(mi - nm);
    M = nm;
  }
  cs[idx * 2] = M;
  cs[idx * 2 + 1] = 1.f / S;
}

__global__ __launch_bounds__(256) void sm_apply(ushort_t* __restrict__ Lb,
                                                const float* __restrict__ cs) {
  // grid (16 jblk, 32 rblk, 2 b): 256 cols x 128 rows per block
  const int tid = threadIdx.x;
  const int b = blockIdx.z;
  const int j0 = blockIdx.x * 256, r0 = blockIdx.y * 128;
  __shared__ float lm[256], lr[256];
  lm[tid] = cs[((size_t)b * 4096 + j0 + tid) * 2];
  lr[tid] = cs[((size_t)b * 4096 + j0 + tid) * 2 + 1];
  __syncthreads();
  const int jj = (tid & 31) * 8;
#pragma unroll
  for (int pass = 0; pass < 16; ++pass) {
    int r = r0 + pass * 8 + (tid >> 5);
    ushort_t* rowp = Lb + (size_t)b * 16777216 + (size_t)r * 4096 + j0 + jj;
    ushort8 u = *(ushort8*)rowp;
#pragma unroll
    for (int i = 0; i < 8; ++i)
      u[i] = f2b(__expf(b2f(u[i]) - lm[jj + i]) * lr[jj + i]);
    *(ushort8*)rowp = u;
  }
}

extern "C" void kernel_launch(void* const* d_in, const int* in_sizes, int n_in,
                              void* d_out, int out_size, void* d_ws,
                              size_t ws_size, hipStream_t stream) {
  const float* x = (const float*)d_in[0];
  const float* gn_w = (const float*)d_in[1];
  const float* gn_b = (const float*)d_in[2];
  const float* qkv_w = (const float*)d_in[3];
  const float* qkv_b = (const float*)d_in[4];
  const float* proj_w = (const float*)d_in[5];
  const float* proj_b = (const float*)d_in[6];
  float* out = (float*)d_out;

  char* ws = (char*)d_ws;
  ushort_t* xnT   = (ushort_t*)(ws);              //  8,388,608  [p][c]
  ushort_t* qkvw  = (ushort_t*)(ws + 8388608);    //  1,572,864
  ushort_t* projw = (ushort_t*)(ws + 9961472);    //    524,288
  float*    stats = (float*)(ws + 10485760);      //        512
  ushort_t* qkT   = (ushort_t*)(ws + 10486272);   // 16,777,216  [p][1024]
  ushort_t* Vb    = (ushort_t*)(ws + 27263488);   //  8,388,608  [c][p]
  ushort_t* Lb    = (ushort_t*)(ws + 35652096);   // 67,108,864  [io][j]
  float*    cs    = (float*)(ws + 102760960);     //     65,536
  float*    smp   = (float*)(ws + 102826496);     //    524,288
  ushort_t* OT    = (ushort_t*)(ws + 103350784);  //  8,388,608  [p][c]

  const float scale = 0.04419417382415922f;  // 1/sqrt(512)

  prep_weights<<<4096, 256, 0, stream>>>(qkv_w, proj_w, qkvw, projw);
  gn_stats<<<64, 256, 0, stream>>>(x, stats);
  gn_apply_t<<<dim3(64, 8, 2), 256, 0, stream>>>(x, gn_w, gn_b, stats, xnT);
  // qkT[p][o] = sum_c xnT[p][c] * qkvw[o][c] + qkv_b[o],  o in [0,1024)
  gemm_bt<0><<<dim3(8, 32, 2), 256, 0, stream>>>(
      xnT, qkvw, qkT, qkv_b, nullptr, 1024, 512, 512, 512,
      2097152, 0, 4194304, 1.f);
  // V[c][p] = sum_c' qkvw[1024+c][c'] * xnT[p][c'] + qkv_b[1024+c]
  gemm_bt<1><<<dim3(32, 4, 2), 256, 0, stream>>>(
      qkvw + 524288, xnT, Vb, qkv_b + 1024, nullptr, 4096, 512, 512, 512,
      0, 2097152, 2097152, 1.f);
  // Lb[io][j] = scale * sum_c qT[io][c] * kT[j][c]   (= attn[j][io])
  gemm_bt<2><<<dim3(32, 32, 2), 256, 0, stream>>>(
      qkT, qkT + 512, Lb, nullptr, nullptr, 4096, 512, 1024, 1024,
      4194304, 4194304, 16777216, scale);
  // column softmax (per j over rows io)
  sm_part<<<dim3(64, 8, 2), 256, 0, stream>>>(Lb, smp);
  sm_fin<<<32, 256, 0, stream>>>(smp, cs);
  sm_apply<<<dim3(16, 32, 2), 256, 0, stream>>>(Lb, cs);
  // OT[p][c] = sum_j P'[p][j] * V[c][j]
  gemm_bt<3><<<dim3(4, 32, 2), 256, 0, stream>>>(
      Lb, Vb, OT, nullptr, nullptr, 512, 4096, 4096, 4096,
      16777216, 2097152, 2097152, 1.f);
  // out[o][p] = sum_c projw[o][c] * OT[p][c] + proj_b[o] + x
  gemm_bt<4><<<dim3(32, 4, 2), 256, 0, stream>>>(
      projw, OT, out, proj_b, x, 4096, 512, 512, 512,
      0, 2097152, 2097152, 1.f);
}